// Round 14
// baseline (89.313 us; speedup 1.0000x reference)
//
#include <hip/hip_runtime.h>
#include <hip/hip_bf16.h>

// Problem constants (SelfAttention_773094113877)
#define LSEQ 2048
#define NB   2
#define NH   16
#define HD   64
#define NKT  32                      // LSEQ / 64 key-tiles
// Q is pre-scaled by log2(e)/sqrt(EMBED) in proj; attn uses native exp2.
#define QSCALE 0.04508687049285173f

typedef __attribute__((ext_vector_type(8)))  __bf16 bf16x8;
typedef __attribute__((ext_vector_type(4)))  __bf16 bf16x4;
typedef __attribute__((ext_vector_type(4)))  float  f32x4;
typedef __attribute__((ext_vector_type(16))) float  f32x16;
typedef __attribute__((ext_vector_type(2)))  unsigned long long u64x2;

// ---------------- mask bit-pack: one wave per 64 keys ----------------
__global__ __launch_bounds__(256)
void pack_mask_kernel(const int* __restrict__ mask,
                      unsigned long long* __restrict__ mbits) {
  size_t gw = ((size_t)blockIdx.x * 256 + threadIdx.x) >> 6;  // word index
  int lane = threadIdx.x & 63;
  int v = mask[gw * 64 + lane];
  unsigned long long b = __ballot(v != 0);
  if (lane == 0) mbits[gw] = b;
}

// ---------------- per-head projection via MFMA (bf16 split-3) ----------------
// V output (z==0) written TRANSPOSED + key-permuted + swizzle-baked for the
// 32x32 PV path: Vtp[d][c]: u=(c>>3)^swzV(d), j=c&7 ->
//   key = (u>>2)*32 + ((j&3) | ((u&1)<<2) | (((u>>1)&1)<<3) | ((j>>2)<<4))
__global__ __launch_bounds__(256)
void proj_kernel(const float* __restrict__ xv, const float* __restrict__ Wv_,
                 const float* __restrict__ xk, const float* __restrict__ Wk_,
                 const float* __restrict__ xq, const float* __restrict__ Wq_,
                 __bf16* __restrict__ outv, __bf16* __restrict__ outk,
                 __bf16* __restrict__ outq) {
  __shared__ __bf16 S[16384];          // 32 KB: Xh|Xl|Wh|Wl; tb aliases Xh/Xl
  __bf16* Xh = S;
  __bf16* Xl = S + 4096;
  __bf16* Wh = S + 8192;
  __bf16* Wl = S + 12288;

  const float* x; const float* W; __bf16* out;
  if (blockIdx.z == 0)      { x = xv; W = Wv_; out = outv; }
  else if (blockIdx.z == 1) { x = xk; W = Wk_; out = outk; }
  else                      { x = xq; W = Wq_; out = outq; }
  const float osc = (blockIdx.z == 2) ? QSCALE : 1.0f;

  const int tid = threadIdx.x;
  const int bx = blockIdx.x;
  const int h  = blockIdx.y;
  const int n  = bx >> 5;
  const int l0 = (bx & 31) << 6;

  const int r  = tid >> 2;
  const int c0 = (tid & 3) << 4;
  const float* xrow = x + ((size_t)(n * LSEQ + l0) + r) * 1024 + h * 64 + c0;
  const float* wrow = W + r * 64 + c0;

#pragma unroll
  for (int hf = 0; hf < 2; ++hf) {
    int kc = c0 + hf * 8;
    int off = r * 64 + (kc ^ ((r & 7) << 3));
    float4 a = *(const float4*)(xrow + hf * 8);
    float4 b = *(const float4*)(xrow + hf * 8 + 4);
    float va[8] = {a.x, a.y, a.z, a.w, b.x, b.y, b.z, b.w};
    bf16x8 hi, lo;
#pragma unroll
    for (int j = 0; j < 8; ++j) {
      __bf16 h_ = (__bf16)va[j];
      hi[j] = h_;
      lo[j] = (__bf16)(va[j] - (float)h_);
    }
    *(bf16x8*)(Xh + off) = hi;
    *(bf16x8*)(Xl + off) = lo;

    float4 c = *(const float4*)(wrow + hf * 8);
    float4 d = *(const float4*)(wrow + hf * 8 + 4);
    float vw[8] = {c.x, c.y, c.z, c.w, d.x, d.y, d.z, d.w};
    bf16x8 whv, wlv;
#pragma unroll
    for (int j = 0; j < 8; ++j) {
      __bf16 h_ = (__bf16)vw[j];
      whv[j] = h_;
      wlv[j] = (__bf16)(vw[j] - (float)h_);
    }
    *(bf16x8*)(Wh + off) = whv;
    *(bf16x8*)(Wl + off) = wlv;
  }
  __syncthreads();

  const int wv   = tid >> 6;
  const int lane = tid & 63;
  const int l15  = lane & 15;
  const int lhi  = lane >> 4;

  bf16x8 xhf[2], xlf[2];
  const int arow = wv * 16 + l15;
#pragma unroll
  for (int ko = 0; ko < 2; ++ko) {
    int aoff = arow * 64 + ((ko * 32 + lhi * 8) ^ ((arow & 7) << 3));
    xhf[ko] = *(const bf16x8*)(Xh + aoff);
    xlf[ko] = *(const bf16x8*)(Xl + aoff);
  }

  f32x4 acc[4] = {};
#pragma unroll
  for (int cg = 0; cg < 4; ++cg) {
    int d = cg * 16 + l15;
#pragma unroll
    for (int ko = 0; ko < 2; ++ko) {
      int boff = d * 64 + ((ko * 32 + lhi * 8) ^ ((d & 7) << 3));
      bf16x8 whf = *(const bf16x8*)(Wh + boff);
      bf16x8 wlf = *(const bf16x8*)(Wl + boff);
      acc[cg] = __builtin_amdgcn_mfma_f32_16x16x32_bf16(xhf[ko], whf, acc[cg], 0, 0, 0);
      acc[cg] = __builtin_amdgcn_mfma_f32_16x16x32_bf16(xhf[ko], wlf, acc[cg], 0, 0, 0);
      acc[cg] = __builtin_amdgcn_mfma_f32_16x16x32_bf16(xlf[ko], whf, acc[cg], 0, 0, 0);
    }
  }
  __syncthreads();

  __bf16* tb = S;                      // [64][72] = [token(key-in-tile)][d]
#pragma unroll
  for (int cg = 0; cg < 4; ++cg)
#pragma unroll
    for (int rr = 0; rr < 4; ++rr)
      tb[(wv * 16 + lhi * 4 + rr) * 72 + cg * 16 + l15] = (__bf16)(acc[cg][rr] * osc);
  __syncthreads();

  if (blockIdx.z == 0) {
    // ---- V: transposed + permuted (32x32 PV mapping) + swizzle-baked ----
    const int d   = tid >> 2;
    const int cg  = tid & 3;
    const int swz = (d & 7) ^ ((d >> 3) & 7);
    __bf16* vout = out + (size_t)(n * NH + h) * (LSEQ * HD)
                 + (size_t)(bx & 31) * 4096 + d * 64 + cg * 16;
    bf16x8 s0, s1;
#pragma unroll
    for (int j16 = 0; j16 < 16; ++j16) {
      int c = cg * 16 + j16;
      int u = (c >> 3) ^ swz;
      int j = c & 7;
      int key = ((u >> 2) << 5) | (j & 3) | ((u & 1) << 2)
              | (((u >> 1) & 1) << 3) | ((j >> 2) << 4);
      __bf16 v_ = tb[key * 72 + d];
      if (j16 < 8) s0[j16] = v_; else s1[j16 - 8] = v_;
    }
    *(bf16x8*)(vout)     = s0;
    *(bf16x8*)(vout + 8) = s1;
  } else {
    const int tok = tid >> 2;
    const int d0  = (tid & 3) * 16;
    bf16x8 o0 = *(const bf16x8*)(tb + tok * 72 + d0);
    bf16x8 o1 = *(const bf16x8*)(tb + tok * 72 + d0 + 8);
    size_t ob = (size_t)(n * NH + h) * LSEQ + l0;
    *(bf16x8*)(out + (ob + tok) * HD + d0)     = o0;
    *(bf16x8*)(out + (ob + tok) * HD + d0 + 8) = o1;
  }
}

// ---------------- fused flash attention (32x32x16 MFMA) ----------------
// grid (16, 32) = 512 blocks, 512 threads = 8 waves.
// K-split: wave = (hw, wq); hw = key-half (32 keys), wq = q-group (32 rows).
// hw=1 waves stage K, hw=0 stage V (both global_load_lds; V pre-permuted).
// 4 K bufs + 4 V bufs (64 KB), one barrier per two 64-key tiles (R11).
// QK: S^T = K·Q^T as 32x32x16 ×4 (K=64 dims). C: row=key=(r&3)+8(r>>2)+4hi5,
// col=q=l&31 -> q lane-local: 1 mask word/lane/tile, bit index compile-time.
// P->PV A-operand lane-local via V key-permutation (baked in proj).
// lsum via MFMA ones. exp2 native; Q pre-scaled.
__global__ __launch_bounds__(512, 4)
void attn_kernel(const __bf16* __restrict__ Qb, const __bf16* __restrict__ Kb,
                 const __bf16* __restrict__ Vtp,
                 const unsigned long long* __restrict__ mbits,
                 float* __restrict__ out) {
  __shared__ __bf16 KV[32768];   // K bufs 0-3 @ b*4096 ; V bufs 0-3 @ 16384+b*4096

  const int tid  = threadIdx.x;
  const int wid  = tid >> 6;
  const int hw   = wid >> 2;           // key-half (0/1)
  const int wq   = wid & 3;            // q-row group
  const int lane = tid & 63;
  const int l31  = lane & 31;
  const int hi5  = lane >> 5;

  // XCD-bijective swizzle: 64 blocks/XCD = 4 heads x 16 q-tiles per XCD
  const int lin = blockIdx.y * 16 + blockIdx.x;    // 0..511
  const int xcd = lin & 7;
  const int idx = lin >> 3;                        // 0..63
  const int nh  = xcd + ((idx >> 4) << 3);
  const int qt  = idx & 15;
  const int n   = nh >> 4;
  const int h   = nh & 15;
  const int q0  = qt << 7;                         // 128 q-rows per block

  const __bf16* Qg = Qb + ((size_t)nh * LSEQ + q0) * HD;
  const __bf16* Kg = Kb + (size_t)nh * LSEQ * HD;
  const __bf16* Vg = Vtp + (size_t)nh * LSEQ * HD;   // [kt][d][col] permuted

  // Q regs (pre-scaled): qrow = wq*32 + l31, dims hi5*8 + 16*ks (ks=0..3)
  const int qrow = wq * 32 + l31;
  bf16x8 qf[4];
#pragma unroll
  for (int ks = 0; ks < 4; ++ks)
    qf[ks] = *(const bf16x8*)(Qg + (size_t)qrow * HD + ks * 16 + hi5 * 8);

  f32x16 o0 = {}, o1 = {}, ols = {};
  const unsigned long long* mrow =
      mbits + ((size_t)n * LSEQ + q0 + qrow) * NKT;

  bf16x8 onesf;
#pragma unroll
  for (int j = 0; j < 8; ++j) onesf[j] = (__bf16)1.0f;

#define STAGE_K(kt_, buf_)                                                         \
  _Pragma("unroll")                                                                \
  for (int it = 0; it < 2; ++it) {                                                 \
    int chb = wq * 64 + it * 256;                                                  \
    int ch = chb + lane;                                                           \
    int skey = ch >> 3, sdc = ch & 7;                                              \
    const __bf16* src = Kg + (size_t)(kt_) * 4096 + skey * 64 + ((sdc ^ (skey & 7)) << 3); \
    __builtin_amdgcn_global_load_lds(                                              \
        (const __attribute__((address_space(1))) void*)src,                        \
        (__attribute__((address_space(3))) void*)(KV + (buf_) * 4096 + chb * 8), 16, 0, 0); \
  }
#define STAGE_V(kt_, buf_)                                                         \
  _Pragma("unroll")                                                                \
  for (int it = 0; it < 2; ++it) {                                                 \
    int chb = wq * 64 + it * 256;                                                  \
    int ch = chb + lane;                                                           \
    const __bf16* src = Vg + (size_t)(kt_) * 4096 + ch * 8;                        \
    __builtin_amdgcn_global_load_lds(                                              \
        (const __attribute__((address_space(1))) void*)src,                        \
        (__attribute__((address_space(3))) void*)(KV + 16384 + (buf_) * 4096 + chb * 8), 16, 0, 0); \
  }

// one 64-key tile from K/V buffer cb_; this wave handles its 32-key half
#define COMPUTE(W_, cb_)                                                           \
  {                                                                                \
    const __bf16* Kc = KV + (cb_) * 4096;                                          \
    const int key = hw * 32 + l31;                                                 \
    f32x16 s = {};                                                                 \
    _Pragma("unroll")                                                              \
    for (int ks = 0; ks < 4; ++ks) {                                               \
      bf16x8 kf = *(const bf16x8*)(                                                \
          Kc + key * 64 + (((2 * ks + hi5) ^ (key & 7)) << 3));                    \
      s = __builtin_amdgcn_mfma_f32_32x32x16_bf16(kf, qf[ks], s, 0, 0, 0);         \
    }                                                                              \
    unsigned half_ = hw ? (unsigned)((W_) >> 32) : (unsigned)(W_);                 \
    unsigned sh = half_ >> (hi5 * 4);                                              \
    bf16x8 pa0, pa1;                                                               \
    _Pragma("unroll")                                                              \
    for (int r = 0; r < 16; ++r) {                                                 \
      float p = __builtin_amdgcn_exp2f(s[r]);                                      \
      p = ((sh >> ((r & 3) + 8 * (r >> 2))) & 1u) ? p : 0.f;                       \
      int j = (r & 3) | ((r >> 3) << 2);                                           \
      if ((r >> 2) & 1) pa1[j] = (__bf16)p; else pa0[j] = (__bf16)p;               \
    }                                                                              \
    const __bf16* Vc = KV + 16384 + (cb_) * 4096;                                  \
    _Pragma("unroll")                                                              \
    for (int dh = 0; dh < 2; ++dh) {                                               \
      int d = dh * 32 + l31;                                                       \
      int swz = (d & 7) ^ ((d >> 3) & 7);                                          \
      bf16x8 vf0 = *(const bf16x8*)(Vc + d * 64 + (((hw * 4 + hi5) ^ swz) << 3));  \
      bf16x8 vf1 = *(const bf16x8*)(Vc + d * 64 + (((hw * 4 + 2 + hi5) ^ swz) << 3)); \
      if (dh == 0) {                                                               \
        o0 = __builtin_amdgcn_mfma_f32_32x32x16_bf16(pa0, vf0, o0, 0, 0, 0);       \
        o0 = __builtin_amdgcn_mfma_f32_32x32x16_bf16(pa1, vf1, o0, 0, 0, 0);       \
      } else {                                                                     \
        o1 = __builtin_amdgcn_mfma_f32_32x32x16_bf16(pa0, vf0, o1, 0, 0, 0);       \
        o1 = __builtin_amdgcn_mfma_f32_32x32x16_bf16(pa1, vf1, o1, 0, 0, 0);       \
      }                                                                            \
    }                                                                              \
    ols = __builtin_amdgcn_mfma_f32_32x32x16_bf16(pa0, onesf, ols, 0, 0, 0);       \
    ols = __builtin_amdgcn_mfma_f32_32x32x16_bf16(pa1, onesf, ols, 0, 0, 0);       \
  }

  // prologue: tiles 0,1 -> bufs 0,1
  if (hw == 1) { STAGE_K(0, 0); STAGE_K(1, 1); }
  else         { STAGE_V(0, 0); STAGE_V(1, 1); }
  u64x2 wm = *(const u64x2*)(mrow);
  __syncthreads();

  for (int p = 0; p < 16; ++p) {
    const int ca = (p & 1) << 1;         // compute bufs {ca, ca+1}
    const int na = ca ^ 2;               // stage bufs   {na, na+1}
    u64x2 nm = {0, 0};
    if (p < 15) {
      if (hw == 1) { STAGE_K(2 * p + 2, na); STAGE_K(2 * p + 3, na + 1); }
      else         { STAGE_V(2 * p + 2, na); STAGE_V(2 * p + 3, na + 1); }
      nm = *(const u64x2*)(mrow + 2 * p + 2);
    }
    COMPUTE(wm[0], ca);
    COMPUTE(wm[1], ca + 1);
    wm = nm;
    __syncthreads();
  }

  // ---- combine halves: hw=1 dumps partials, hw=0 adds + stores ----
  float* Sf  = (float*)KV;             // o partials: 8192 floats (32 KB)
  float* Sl  = Sf + 8192;              // lsum partials: 4096 floats (16 KB)
  if (hw == 1) {
#pragma unroll
    for (int r = 0; r < 16; ++r) {
      Sf[((wq * 2 + 0) * 16 + r) * 64 + lane] = o0[r];
      Sf[((wq * 2 + 1) * 16 + r) * 64 + lane] = o1[r];
      Sl[(wq * 16 + r) * 64 + lane] = ols[r];
    }
  }
  __syncthreads();
  if (hw == 0) {
#pragma unroll
    for (int r = 0; r < 16; ++r) {
      float po0 = Sf[((wq * 2 + 0) * 16 + r) * 64 + lane];
      float po1 = Sf[((wq * 2 + 1) * 16 + r) * 64 + lane];
      float pls = Sl[(wq * 16 + r) * 64 + lane];
      float inv = 1.f / (ols[r] + pls);
      int qr = (r & 3) + 8 * (r >> 2) + 4 * hi5;
      size_t ob = ((size_t)n * LSEQ + q0 + wq * 32 + qr) * 1024 + h * 64 + l31;
      out[ob]      = (o0[r] + po0) * inv;
      out[ob + 32] = (o1[r] + po1) * inv;
    }
  }
#undef STAGE_K
#undef STAGE_V
#undef COMPUTE
}

extern "C" void kernel_launch(void* const* d_in, const int* in_sizes, int n_in,
                              void* d_out, int out_size, void* d_ws, size_t ws_size,
                              hipStream_t stream) {
  const float* xv   = (const float*)d_in[0];   // values
  const float* xk   = (const float*)d_in[1];   // keys
  const float* xq   = (const float*)d_in[2];   // queries
  const int*   mask = (const int*)d_in[3];
  const float* Wv   = (const float*)d_in[4];
  const float* Wk   = (const float*)d_in[5];
  const float* Wq   = (const float*)d_in[6];
  float* out = (float*)d_out;

  const size_t elems = (size_t)NB * NH * LSEQ * HD;       // 4,194,304
  __bf16* Qw = (__bf16*)d_ws;
  __bf16* Kw = Qw + elems;
  __bf16* Vw = Kw + elems;          // holds permuted/transposed Vtp layout
  unsigned long long* mb = (unsigned long long*)(Vw + elems);  // 1 MB

  pack_mask_kernel<<<dim3(NB * LSEQ * NKT / 4), 256, 0, stream>>>(mask, mb);
  proj_kernel<<<dim3(64, NH, 3), 256, 0, stream>>>(xv, Wv, xk, Wk, xq, Wq,
                                                   Vw, Kw, Qw);
  attn_kernel<<<dim3(16, 32), 512, 0, stream>>>(Qw, Kw, Vw, mb, out);
}

// Round 15
// 88.725 us; speedup vs baseline: 1.0066x; 1.0066x over previous
//
#include <hip/hip_runtime.h>
#include <hip/hip_bf16.h>

// Problem constants (SelfAttention_773094113877)
#define LSEQ 2048
#define NB   2
#define NH   16
#define HD   64
#define NKT  32                      // LSEQ / 64 key-tiles
// Q is pre-scaled by log2(e)/sqrt(EMBED) in proj; attn uses native exp2.
#define QSCALE 0.04508687049285173f

typedef __attribute__((ext_vector_type(8)))  __bf16 bf16x8;
typedef __attribute__((ext_vector_type(4)))  __bf16 bf16x4;
typedef __attribute__((ext_vector_type(4)))  float  f32x4;
typedef __attribute__((ext_vector_type(16))) float  f32x16;
typedef __attribute__((ext_vector_type(2)))  unsigned long long u64x2;

// ---------------- mask bit-pack: one wave per 64 keys ----------------
__global__ __launch_bounds__(256)
void pack_mask_kernel(const int* __restrict__ mask,
                      unsigned long long* __restrict__ mbits) {
  size_t gw = ((size_t)blockIdx.x * 256 + threadIdx.x) >> 6;  // word index
  int lane = threadIdx.x & 63;
  int v = mask[gw * 64 + lane];
  unsigned long long b = __ballot(v != 0);
  if (lane == 0) mbits[gw] = b;
}

// ---------------- per-head projection via MFMA (bf16 split-3) ----------------
// V output (z==0) written TRANSPOSED + key-permuted + swizzle-baked for the
// 32x32 PV path: Vtp[d][c]: u=(c>>3)^swzV(d), j=c&7 ->
//   key = (u>>2)*32 + ((j&3) | ((u&1)<<2) | (((u>>1)&1)<<3) | ((j>>2)<<4))
__global__ __launch_bounds__(256)
void proj_kernel(const float* __restrict__ xv, const float* __restrict__ Wv_,
                 const float* __restrict__ xk, const float* __restrict__ Wk_,
                 const float* __restrict__ xq, const float* __restrict__ Wq_,
                 __bf16* __restrict__ outv, __bf16* __restrict__ outk,
                 __bf16* __restrict__ outq) {
  __shared__ __bf16 S[16384];          // 32 KB: Xh|Xl|Wh|Wl; tb aliases Xh/Xl
  __bf16* Xh = S;
  __bf16* Xl = S + 4096;
  __bf16* Wh = S + 8192;
  __bf16* Wl = S + 12288;

  const float* x; const float* W; __bf16* out;
  if (blockIdx.z == 0)      { x = xv; W = Wv_; out = outv; }
  else if (blockIdx.z == 1) { x = xk; W = Wk_; out = outk; }
  else                      { x = xq; W = Wq_; out = outq; }
  const float osc = (blockIdx.z == 2) ? QSCALE : 1.0f;

  const int tid = threadIdx.x;
  const int bx = blockIdx.x;
  const int h  = blockIdx.y;
  const int n  = bx >> 5;
  const int l0 = (bx & 31) << 6;

  const int r  = tid >> 2;
  const int c0 = (tid & 3) << 4;
  const float* xrow = x + ((size_t)(n * LSEQ + l0) + r) * 1024 + h * 64 + c0;
  const float* wrow = W + r * 64 + c0;

#pragma unroll
  for (int hf = 0; hf < 2; ++hf) {
    int kc = c0 + hf * 8;
    int off = r * 64 + (kc ^ ((r & 7) << 3));
    float4 a = *(const float4*)(xrow + hf * 8);
    float4 b = *(const float4*)(xrow + hf * 8 + 4);
    float va[8] = {a.x, a.y, a.z, a.w, b.x, b.y, b.z, b.w};
    bf16x8 hi, lo;
#pragma unroll
    for (int j = 0; j < 8; ++j) {
      __bf16 h_ = (__bf16)va[j];
      hi[j] = h_;
      lo[j] = (__bf16)(va[j] - (float)h_);
    }
    *(bf16x8*)(Xh + off) = hi;
    *(bf16x8*)(Xl + off) = lo;

    float4 c = *(const float4*)(wrow + hf * 8);
    float4 d = *(const float4*)(wrow + hf * 8 + 4);
    float vw[8] = {c.x, c.y, c.z, c.w, d.x, d.y, d.z, d.w};
    bf16x8 whv, wlv;
#pragma unroll
    for (int j = 0; j < 8; ++j) {
      __bf16 h_ = (__bf16)vw[j];
      whv[j] = h_;
      wlv[j] = (__bf16)(vw[j] - (float)h_);
    }
    *(bf16x8*)(Wh + off) = whv;
    *(bf16x8*)(Wl + off) = wlv;
  }
  __syncthreads();

  const int wv   = tid >> 6;
  const int lane = tid & 63;
  const int l15  = lane & 15;
  const int lhi  = lane >> 4;

  bf16x8 xhf[2], xlf[2];
  const int arow = wv * 16 + l15;
#pragma unroll
  for (int ko = 0; ko < 2; ++ko) {
    int aoff = arow * 64 + ((ko * 32 + lhi * 8) ^ ((arow & 7) << 3));
    xhf[ko] = *(const bf16x8*)(Xh + aoff);
    xlf[ko] = *(const bf16x8*)(Xl + aoff);
  }

  f32x4 acc[4] = {};
#pragma unroll
  for (int cg = 0; cg < 4; ++cg) {
    int d = cg * 16 + l15;
#pragma unroll
    for (int ko = 0; ko < 2; ++ko) {
      int boff = d * 64 + ((ko * 32 + lhi * 8) ^ ((d & 7) << 3));
      bf16x8 whf = *(const bf16x8*)(Wh + boff);
      bf16x8 wlf = *(const bf16x8*)(Wl + boff);
      acc[cg] = __builtin_amdgcn_mfma_f32_16x16x32_bf16(xhf[ko], whf, acc[cg], 0, 0, 0);
      acc[cg] = __builtin_amdgcn_mfma_f32_16x16x32_bf16(xhf[ko], wlf, acc[cg], 0, 0, 0);
      acc[cg] = __builtin_amdgcn_mfma_f32_16x16x32_bf16(xlf[ko], whf, acc[cg], 0, 0, 0);
    }
  }
  __syncthreads();

  __bf16* tb = S;                      // [64][72] = [token(key-in-tile)][d]
#pragma unroll
  for (int cg = 0; cg < 4; ++cg)
#pragma unroll
    for (int rr = 0; rr < 4; ++rr)
      tb[(wv * 16 + lhi * 4 + rr) * 72 + cg * 16 + l15] = (__bf16)(acc[cg][rr] * osc);
  __syncthreads();

  if (blockIdx.z == 0) {
    // ---- V: transposed + permuted (32x32 PV mapping) + swizzle-baked ----
    const int d   = tid >> 2;
    const int cg  = tid & 3;
    const int swz = (d & 7) ^ ((d >> 3) & 7);
    __bf16* vout = out + (size_t)(n * NH + h) * (LSEQ * HD)
                 + (size_t)(bx & 31) * 4096 + d * 64 + cg * 16;
    bf16x8 s0, s1;
#pragma unroll
    for (int j16 = 0; j16 < 16; ++j16) {
      int c = cg * 16 + j16;
      int u = (c >> 3) ^ swz;
      int j = c & 7;
      int key = ((u >> 2) << 5) | (j & 3) | ((u & 1) << 2)
              | (((u >> 1) & 1) << 3) | ((j >> 2) << 4);
      __bf16 v_ = tb[key * 72 + d];
      if (j16 < 8) s0[j16] = v_; else s1[j16 - 8] = v_;
    }
    *(bf16x8*)(vout)     = s0;
    *(bf16x8*)(vout + 8) = s1;
  } else {
    const int tok = tid >> 2;
    const int d0  = (tid & 3) * 16;
    bf16x8 o0 = *(const bf16x8*)(tb + tok * 72 + d0);
    bf16x8 o1 = *(const bf16x8*)(tb + tok * 72 + d0 + 8);
    size_t ob = (size_t)(n * NH + h) * LSEQ + l0;
    *(bf16x8*)(out + (ob + tok) * HD + d0)     = o0;
    *(bf16x8*)(out + (ob + tok) * HD + d0 + 8) = o1;
  }
}

// ---------------- fused flash attention (32x32x16 MFMA) ----------------
// grid (16, 32) = 512 blocks, 512 threads = 8 waves.
// K-split: wave = (hw, wq); hw = key-half (32 keys), wq = q-group (32 rows).
// hw=1 waves stage K, hw=0 stage V (both global_load_lds; V pre-permuted).
// 4 K bufs + 4 V bufs (64 KB), one barrier per two 64-key tiles (R11).
// PHASE STAGGER: odd-wq waves compute tile B then A; even waves A then B.
// -> at any instant half the waves are in MFMA phase, half in softmax VALU
//    phase: pipes co-busy instead of lockstep alternation.
// QK: S^T = K·Q^T 32x32x16 ×4. q lane-local -> 1 mask word/lane/tile.
// P->PV A-operand lane-local via V key-permutation (baked in proj).
// lsum via MFMA ones. exp2 native; Q pre-scaled.
__global__ __launch_bounds__(512, 4)
void attn_kernel(const __bf16* __restrict__ Qb, const __bf16* __restrict__ Kb,
                 const __bf16* __restrict__ Vtp,
                 const unsigned long long* __restrict__ mbits,
                 float* __restrict__ out) {
  __shared__ __bf16 KV[32768];   // K bufs 0-3 @ b*4096 ; V bufs 0-3 @ 16384+b*4096

  const int tid  = threadIdx.x;
  const int wid  = tid >> 6;
  const int hw   = wid >> 2;           // key-half (0/1)
  const int wq   = wid & 3;            // q-row group
  const int lane = tid & 63;
  const int l31  = lane & 31;
  const int hi5  = lane >> 5;

  // XCD-bijective swizzle: 64 blocks/XCD = 4 heads x 16 q-tiles per XCD
  const int lin = blockIdx.y * 16 + blockIdx.x;    // 0..511
  const int xcd = lin & 7;
  const int idx = lin >> 3;                        // 0..63
  const int nh  = xcd + ((idx >> 4) << 3);
  const int qt  = idx & 15;
  const int n   = nh >> 4;
  const int h   = nh & 15;
  const int q0  = qt << 7;                         // 128 q-rows per block

  const __bf16* Qg = Qb + ((size_t)nh * LSEQ + q0) * HD;
  const __bf16* Kg = Kb + (size_t)nh * LSEQ * HD;
  const __bf16* Vg = Vtp + (size_t)nh * LSEQ * HD;   // [kt][d][col] permuted

  // Q regs (pre-scaled): qrow = wq*32 + l31, dims hi5*8 + 16*ks (ks=0..3)
  const int qrow = wq * 32 + l31;
  bf16x8 qf[4];
#pragma unroll
  for (int ks = 0; ks < 4; ++ks)
    qf[ks] = *(const bf16x8*)(Qg + (size_t)qrow * HD + ks * 16 + hi5 * 8);

  f32x16 o0 = {}, o1 = {}, ols = {};
  const unsigned long long* mrow =
      mbits + ((size_t)n * LSEQ + q0 + qrow) * NKT;

  bf16x8 onesf;
#pragma unroll
  for (int j = 0; j < 8; ++j) onesf[j] = (__bf16)1.0f;

#define STAGE_K(kt_, buf_)                                                         \
  _Pragma("unroll")                                                                \
  for (int it = 0; it < 2; ++it) {                                                 \
    int chb = wq * 64 + it * 256;                                                  \
    int ch = chb + lane;                                                           \
    int skey = ch >> 3, sdc = ch & 7;                                              \
    const __bf16* src = Kg + (size_t)(kt_) * 4096 + skey * 64 + ((sdc ^ (skey & 7)) << 3); \
    __builtin_amdgcn_global_load_lds(                                              \
        (const __attribute__((address_space(1))) void*)src,                        \
        (__attribute__((address_space(3))) void*)(KV + (buf_) * 4096 + chb * 8), 16, 0, 0); \
  }
#define STAGE_V(kt_, buf_)                                                         \
  _Pragma("unroll")                                                                \
  for (int it = 0; it < 2; ++it) {                                                 \
    int chb = wq * 64 + it * 256;                                                  \
    int ch = chb + lane;                                                           \
    const __bf16* src = Vg + (size_t)(kt_) * 4096 + ch * 8;                        \
    __builtin_amdgcn_global_load_lds(                                              \
        (const __attribute__((address_space(1))) void*)src,                        \
        (__attribute__((address_space(3))) void*)(KV + 16384 + (buf_) * 4096 + chb * 8), 16, 0, 0); \
  }

// one 64-key tile from K/V buffer cb_; this wave handles its 32-key half
#define COMPUTE(W_, cb_)                                                           \
  {                                                                                \
    const __bf16* Kc = KV + (cb_) * 4096;                                          \
    const int key = hw * 32 + l31;                                                 \
    f32x16 s = {};                                                                 \
    _Pragma("unroll")                                                              \
    for (int ks = 0; ks < 4; ++ks) {                                               \
      bf16x8 kf = *(const bf16x8*)(                                                \
          Kc + key * 64 + (((2 * ks + hi5) ^ (key & 7)) << 3));                    \
      s = __builtin_amdgcn_mfma_f32_32x32x16_bf16(kf, qf[ks], s, 0, 0, 0);         \
    }                                                                              \
    unsigned half_ = hw ? (unsigned)((W_) >> 32) : (unsigned)(W_);                 \
    unsigned sh = half_ >> (hi5 * 4);                                              \
    bf16x8 pa0, pa1;                                                               \
    _Pragma("unroll")                                                              \
    for (int r = 0; r < 16; ++r) {                                                 \
      float p = __builtin_amdgcn_exp2f(s[r]);                                      \
      p = ((sh >> ((r & 3) + 8 * (r >> 2))) & 1u) ? p : 0.f;                       \
      int j = (r & 3) | ((r >> 3) << 2);                                           \
      if ((r >> 2) & 1) pa1[j] = (__bf16)p; else pa0[j] = (__bf16)p;               \
    }                                                                              \
    const __bf16* Vc = KV + 16384 + (cb_) * 4096;                                  \
    _Pragma("unroll")                                                              \
    for (int dh = 0; dh < 2; ++dh) {                                               \
      int d = dh * 32 + l31;                                                       \
      int swz = (d & 7) ^ ((d >> 3) & 7);                                          \
      bf16x8 vf0 = *(const bf16x8*)(Vc + d * 64 + (((hw * 4 + hi5) ^ swz) << 3));  \
      bf16x8 vf1 = *(const bf16x8*)(Vc + d * 64 + (((hw * 4 + 2 + hi5) ^ swz) << 3)); \
      if (dh == 0) {                                                               \
        o0 = __builtin_amdgcn_mfma_f32_32x32x16_bf16(pa0, vf0, o0, 0, 0, 0);       \
        o0 = __builtin_amdgcn_mfma_f32_32x32x16_bf16(pa1, vf1, o0, 0, 0, 0);       \
      } else {                                                                     \
        o1 = __builtin_amdgcn_mfma_f32_32x32x16_bf16(pa0, vf0, o1, 0, 0, 0);       \
        o1 = __builtin_amdgcn_mfma_f32_32x32x16_bf16(pa1, vf1, o1, 0, 0, 0);       \
      }                                                                            \
    }                                                                              \
    ols = __builtin_amdgcn_mfma_f32_32x32x16_bf16(pa0, onesf, ols, 0, 0, 0);       \
    ols = __builtin_amdgcn_mfma_f32_32x32x16_bf16(pa1, onesf, ols, 0, 0, 0);       \
  }

  // prologue: tiles 0,1 -> bufs 0,1
  if (hw == 1) { STAGE_K(0, 0); STAGE_K(1, 1); }
  else         { STAGE_V(0, 0); STAGE_V(1, 1); }
  u64x2 wm = *(const u64x2*)(mrow);
  __syncthreads();

  for (int p = 0; p < 16; ++p) {
    const int ca = (p & 1) << 1;         // compute bufs {ca, ca+1}
    const int na = ca ^ 2;               // stage bufs   {na, na+1}
    u64x2 nm = {0, 0};
    if (p < 15) {
      if (hw == 1) { STAGE_K(2 * p + 2, na); STAGE_K(2 * p + 3, na + 1); }
      else         { STAGE_V(2 * p + 2, na); STAGE_V(2 * p + 3, na + 1); }
      nm = *(const u64x2*)(mrow + 2 * p + 2);
    }
    // phase stagger: odd-wq waves take tile B first -> half the waves are in
    // MFMA phase while the other half are in softmax VALU phase.
    if (wq & 1) {
      COMPUTE(wm[1], ca + 1);
      COMPUTE(wm[0], ca);
    } else {
      COMPUTE(wm[0], ca);
      COMPUTE(wm[1], ca + 1);
    }
    wm = nm;
    __syncthreads();
  }

  // ---- combine halves: hw=1 dumps partials, hw=0 adds + stores ----
  float* Sf  = (float*)KV;             // o partials: 8192 floats (32 KB)
  float* Sl  = Sf + 8192;              // lsum partials: 4096 floats (16 KB)
  if (hw == 1) {
#pragma unroll
    for (int r = 0; r < 16; ++r) {
      Sf[((wq * 2 + 0) * 16 + r) * 64 + lane] = o0[r];
      Sf[((wq * 2 + 1) * 16 + r) * 64 + lane] = o1[r];
      Sl[(wq * 16 + r) * 64 + lane] = ols[r];
    }
  }
  __syncthreads();
  if (hw == 0) {
#pragma unroll
    for (int r = 0; r < 16; ++r) {
      float po0 = Sf[((wq * 2 + 0) * 16 + r) * 64 + lane];
      float po1 = Sf[((wq * 2 + 1) * 16 + r) * 64 + lane];
      float pls = Sl[(wq * 16 + r) * 64 + lane];
      float inv = 1.f / (ols[r] + pls);
      int qr = (r & 3) + 8 * (r >> 2) + 4 * hi5;
      size_t ob = ((size_t)n * LSEQ + q0 + wq * 32 + qr) * 1024 + h * 64 + l31;
      out[ob]      = (o0[r] + po0) * inv;
      out[ob + 32] = (o1[r] + po1) * inv;
    }
  }
#undef STAGE_K
#undef STAGE_V
#undef COMPUTE
}

extern "C" void kernel_launch(void* const* d_in, const int* in_sizes, int n_in,
                              void* d_out, int out_size, void* d_ws, size_t ws_size,
                              hipStream_t stream) {
  const float* xv   = (const float*)d_in[0];   // values
  const float* xk   = (const float*)d_in[1];   // keys
  const float* xq   = (const float*)d_in[2];   // queries
  const int*   mask = (const int*)d_in[3];
  const float* Wv   = (const float*)d_in[4];
  const float* Wk   = (const float*)d_in[5];
  const float* Wq   = (const float*)d_in[6];
  float* out = (float*)d_out;

  const size_t elems = (size_t)NB * NH * LSEQ * HD;       // 4,194,304
  __bf16* Qw = (__bf16*)d_ws;
  __bf16* Kw = Qw + elems;
  __bf16* Vw = Kw + elems;          // holds permuted/transposed Vtp layout
  unsigned long long* mb = (unsigned long long*)(Vw + elems);  // 1 MB

  pack_mask_kernel<<<dim3(NB * LSEQ * NKT / 4), 256, 0, stream>>>(mask, mb);
  proj_kernel<<<dim3(64, NH, 3), 256, 0, stream>>>(xv, Wv, xk, Wk, xq, Wq,
                                                   Vw, Kw, Qw);
  attn_kernel<<<dim3(16, 32), 512, 0, stream>>>(Qw, Kw, Vw, mb, out);
}

// Round 16
// 86.401 us; speedup vs baseline: 1.0337x; 1.0269x over previous
//
#include <hip/hip_runtime.h>
#include <hip/hip_bf16.h>

// Problem constants (SelfAttention_773094113877)
#define LSEQ 2048
#define NB   2
#define NH   16
#define HD   64
#define NKT  32                      // LSEQ / 64 key-tiles
// Q is pre-scaled by log2(e)/sqrt(EMBED) in proj; attn uses native exp2.
#define QSCALE 0.04508687049285173f

typedef __attribute__((ext_vector_type(8)))  __bf16 bf16x8;
typedef __attribute__((ext_vector_type(4)))  __bf16 bf16x4;
typedef __attribute__((ext_vector_type(4)))  float  f32x4;
typedef __attribute__((ext_vector_type(16))) float  f32x16;
typedef __attribute__((ext_vector_type(2)))  unsigned long long u64x2;

// ------- fused pre-pass: proj (z=0,1,2) + mask bit-pack (z=3) -------
// proj: out[nh][l][d] = x @ W.T via MFMA bf16 split-3 (hi/lo), fp32-equivalent.
// V output (z==0) written TRANSPOSED + key-permuted + swizzle-baked for the
// 32x32 PV path: Vtp[d][c]: u=(c>>3)^swzV(d), j=c&7 ->
//   key = (u>>2)*32 + ((j&3) | ((u&1)<<2) | (((u>>1)&1)<<3) | ((j>>2)<<4))
// pack (z==3): mbits[g] = ballot(mask[g*64+lane] != 0), 32 words/wave.
__global__ __launch_bounds__(256)
void proj_kernel(const float* __restrict__ xv, const float* __restrict__ Wv_,
                 const float* __restrict__ xk, const float* __restrict__ Wk_,
                 const float* __restrict__ xq, const float* __restrict__ Wq_,
                 const int* __restrict__ mask,
                 __bf16* __restrict__ outv, __bf16* __restrict__ outk,
                 __bf16* __restrict__ outq,
                 unsigned long long* __restrict__ mbits) {
  __shared__ __bf16 S[16384];          // 32 KB: Xh|Xl|Wh|Wl; tb aliases Xh/Xl

  const int tid = threadIdx.x;

  if (blockIdx.z == 3) {
    // ---- mask bit-pack: 1024 blocks x 8192 ints each ----
    const int bid  = blockIdx.x * NH + blockIdx.y;     // 0..1023
    const int w    = tid >> 6;
    const int lane = tid & 63;
    const size_t wbase = (size_t)bid * 128 + w * 32;   // word index base
#pragma unroll
    for (int i = 0; i < 8; ++i) {
      size_t g0 = wbase + i * 4;
#pragma unroll
      for (int j = 0; j < 4; ++j) {
        int v = mask[(g0 + j) * 64 + lane];
        unsigned long long b = __ballot(v != 0);
        if (lane == 0) mbits[g0 + j] = b;
      }
    }
    return;
  }

  __bf16* Xh = S;
  __bf16* Xl = S + 4096;
  __bf16* Wh = S + 8192;
  __bf16* Wl = S + 12288;

  const float* x; const float* W; __bf16* out;
  if (blockIdx.z == 0)      { x = xv; W = Wv_; out = outv; }
  else if (blockIdx.z == 1) { x = xk; W = Wk_; out = outk; }
  else                      { x = xq; W = Wq_; out = outq; }
  const float osc = (blockIdx.z == 2) ? QSCALE : 1.0f;

  const int bx = blockIdx.x;
  const int h  = blockIdx.y;
  const int n  = bx >> 5;
  const int l0 = (bx & 31) << 6;

  const int r  = tid >> 2;
  const int c0 = (tid & 3) << 4;
  const float* xrow = x + ((size_t)(n * LSEQ + l0) + r) * 1024 + h * 64 + c0;
  const float* wrow = W + r * 64 + c0;

#pragma unroll
  for (int hf = 0; hf < 2; ++hf) {
    int kc = c0 + hf * 8;
    int off = r * 64 + (kc ^ ((r & 7) << 3));
    float4 a = *(const float4*)(xrow + hf * 8);
    float4 b = *(const float4*)(xrow + hf * 8 + 4);
    float va[8] = {a.x, a.y, a.z, a.w, b.x, b.y, b.z, b.w};
    bf16x8 hi, lo;
#pragma unroll
    for (int j = 0; j < 8; ++j) {
      __bf16 h_ = (__bf16)va[j];
      hi[j] = h_;
      lo[j] = (__bf16)(va[j] - (float)h_);
    }
    *(bf16x8*)(Xh + off) = hi;
    *(bf16x8*)(Xl + off) = lo;

    float4 c = *(const float4*)(wrow + hf * 8);
    float4 d = *(const float4*)(wrow + hf * 8 + 4);
    float vw[8] = {c.x, c.y, c.z, c.w, d.x, d.y, d.z, d.w};
    bf16x8 whv, wlv;
#pragma unroll
    for (int j = 0; j < 8; ++j) {
      __bf16 h_ = (__bf16)vw[j];
      whv[j] = h_;
      wlv[j] = (__bf16)(vw[j] - (float)h_);
    }
    *(bf16x8*)(Wh + off) = whv;
    *(bf16x8*)(Wl + off) = wlv;
  }
  __syncthreads();

  const int wv   = tid >> 6;
  const int lane = tid & 63;
  const int l15  = lane & 15;
  const int lhi  = lane >> 4;

  bf16x8 xhf[2], xlf[2];
  const int arow = wv * 16 + l15;
#pragma unroll
  for (int ko = 0; ko < 2; ++ko) {
    int aoff = arow * 64 + ((ko * 32 + lhi * 8) ^ ((arow & 7) << 3));
    xhf[ko] = *(const bf16x8*)(Xh + aoff);
    xlf[ko] = *(const bf16x8*)(Xl + aoff);
  }

  f32x4 acc[4] = {};
#pragma unroll
  for (int cg = 0; cg < 4; ++cg) {
    int d = cg * 16 + l15;
#pragma unroll
    for (int ko = 0; ko < 2; ++ko) {
      int boff = d * 64 + ((ko * 32 + lhi * 8) ^ ((d & 7) << 3));
      bf16x8 whf = *(const bf16x8*)(Wh + boff);
      bf16x8 wlf = *(const bf16x8*)(Wl + boff);
      acc[cg] = __builtin_amdgcn_mfma_f32_16x16x32_bf16(xhf[ko], whf, acc[cg], 0, 0, 0);
      acc[cg] = __builtin_amdgcn_mfma_f32_16x16x32_bf16(xhf[ko], wlf, acc[cg], 0, 0, 0);
      acc[cg] = __builtin_amdgcn_mfma_f32_16x16x32_bf16(xlf[ko], whf, acc[cg], 0, 0, 0);
    }
  }
  __syncthreads();

  __bf16* tb = S;                      // [64][72] = [token(key-in-tile)][d]
#pragma unroll
  for (int cg = 0; cg < 4; ++cg)
#pragma unroll
    for (int rr = 0; rr < 4; ++rr)
      tb[(wv * 16 + lhi * 4 + rr) * 72 + cg * 16 + l15] = (__bf16)(acc[cg][rr] * osc);
  __syncthreads();

  if (blockIdx.z == 0) {
    // ---- V: transposed + permuted (32x32 PV mapping) + swizzle-baked ----
    const int d   = tid >> 2;
    const int cg  = tid & 3;
    const int swz = (d & 7) ^ ((d >> 3) & 7);
    __bf16* vout = out + (size_t)(n * NH + h) * (LSEQ * HD)
                 + (size_t)(bx & 31) * 4096 + d * 64 + cg * 16;
    bf16x8 s0, s1;
#pragma unroll
    for (int j16 = 0; j16 < 16; ++j16) {
      int c = cg * 16 + j16;
      int u = (c >> 3) ^ swz;
      int j = c & 7;
      int key = ((u >> 2) << 5) | (j & 3) | ((u & 1) << 2)
              | (((u >> 1) & 1) << 3) | ((j >> 2) << 4);
      __bf16 v_ = tb[key * 72 + d];
      if (j16 < 8) s0[j16] = v_; else s1[j16 - 8] = v_;
    }
    *(bf16x8*)(vout)     = s0;
    *(bf16x8*)(vout + 8) = s1;
  } else {
    const int tok = tid >> 2;
    const int d0  = (tid & 3) * 16;
    bf16x8 o0 = *(const bf16x8*)(tb + tok * 72 + d0);
    bf16x8 o1 = *(const bf16x8*)(tb + tok * 72 + d0 + 8);
    size_t ob = (size_t)(n * NH + h) * LSEQ + l0;
    *(bf16x8*)(out + (ob + tok) * HD + d0)     = o0;
    *(bf16x8*)(out + (ob + tok) * HD + d0 + 8) = o1;
  }
}

// ---------------- fused flash attention (32x32x16 MFMA) ----------------
// grid (16, 32) = 512 blocks, 512 threads = 8 waves.
// K-split: wave = (hw, wq); hw = key-half (32 keys), wq = q-group (32 rows).
// hw=1 waves stage K, hw=0 stage V (both global_load_lds; V pre-permuted).
// 4 K bufs + 4 V bufs (64 KB), one barrier per two 64-key tiles (R11).
// ADDRESSING HOIST: 8 per-lane LDS pointers precomputed once; 2-period loop
// unroll makes buffer indices compile-time -> ds_read = base + imm offset,
// zero per-tile address VALU.
// QK: S^T = K·Q^T 32x32x16 ×4. q lane-local -> 1 mask word/lane/tile.
// P->PV A-operand lane-local via V key-permutation (baked in proj).
// lsum via MFMA ones. exp2 native; Q pre-scaled.
__global__ __launch_bounds__(512, 4)
void attn_kernel(const __bf16* __restrict__ Qb, const __bf16* __restrict__ Kb,
                 const __bf16* __restrict__ Vtp,
                 const unsigned long long* __restrict__ mbits,
                 float* __restrict__ out) {
  __shared__ __bf16 KV[32768];   // K bufs 0-3 @ b*4096 ; V bufs 0-3 @ 16384+b*4096

  const int tid  = threadIdx.x;
  const int wid  = tid >> 6;
  const int hw   = wid >> 2;           // key-half (0/1)
  const int wq   = wid & 3;            // q-row group
  const int lane = tid & 63;
  const int l31  = lane & 31;
  const int hi5  = lane >> 5;

  // XCD-bijective swizzle: 64 blocks/XCD = 4 heads x 16 q-tiles per XCD
  const int lin = blockIdx.y * 16 + blockIdx.x;    // 0..511
  const int xcd = lin & 7;
  const int idx = lin >> 3;                        // 0..63
  const int nh  = xcd + ((idx >> 4) << 3);
  const int qt  = idx & 15;
  const int n   = nh >> 4;
  const int h   = nh & 15;
  const int q0  = qt << 7;                         // 128 q-rows per block

  const __bf16* Qg = Qb + ((size_t)nh * LSEQ + q0) * HD;
  const __bf16* Kg = Kb + (size_t)nh * LSEQ * HD;
  const __bf16* Vg = Vtp + (size_t)nh * LSEQ * HD;   // [kt][d][col] permuted

  // Q regs (pre-scaled): qrow = wq*32 + l31, dims hi5*8 + 16*ks (ks=0..3)
  const int qrow = wq * 32 + l31;
  bf16x8 qf[4];
#pragma unroll
  for (int ks = 0; ks < 4; ++ks)
    qf[ks] = *(const bf16x8*)(Qg + (size_t)qrow * HD + ks * 16 + hi5 * 8);

  f32x16 o0 = {}, o1 = {}, ols = {};
  const unsigned long long* mrow =
      mbits + ((size_t)n * LSEQ + q0 + qrow) * NKT;

  bf16x8 onesf;
#pragma unroll
  for (int j = 0; j < 8; ++j) onesf[j] = (__bf16)1.0f;

  // ---- hoisted per-lane LDS pointers (buffer 0 bases; buf b = +b*4096) ----
  const int key = hw * 32 + l31;
  const __bf16* kp[4];
#pragma unroll
  for (int ks = 0; ks < 4; ++ks)
    kp[ks] = &KV[key * 64 + (((2 * ks + hi5) ^ (key & 7)) << 3)];
  const __bf16* vp[4];
#pragma unroll
  for (int dh = 0; dh < 2; ++dh) {
    int d = dh * 32 + l31;
    int swz = (d & 7) ^ ((d >> 3) & 7);
    vp[dh * 2 + 0] = &KV[16384 + d * 64 + (((hw * 4 + hi5) ^ swz) << 3)];
    vp[dh * 2 + 1] = &KV[16384 + d * 64 + (((hw * 4 + 2 + hi5) ^ swz) << 3)];
  }

#define STAGE_K(kt_, buf_)                                                         \
  _Pragma("unroll")                                                                \
  for (int it = 0; it < 2; ++it) {                                                 \
    int chb = wq * 64 + it * 256;                                                  \
    int ch = chb + lane;                                                           \
    int skey = ch >> 3, sdc = ch & 7;                                              \
    const __bf16* src = Kg + (size_t)(kt_) * 4096 + skey * 64 + ((sdc ^ (skey & 7)) << 3); \
    __builtin_amdgcn_global_load_lds(                                              \
        (const __attribute__((address_space(1))) void*)src,                        \
        (__attribute__((address_space(3))) void*)(KV + (buf_) * 4096 + chb * 8), 16, 0, 0); \
  }
#define STAGE_V(kt_, buf_)                                                         \
  _Pragma("unroll")                                                                \
  for (int it = 0; it < 2; ++it) {                                                 \
    int chb = wq * 64 + it * 256;                                                  \
    int ch = chb + lane;                                                           \
    const __bf16* src = Vg + (size_t)(kt_) * 4096 + ch * 8;                        \
    __builtin_amdgcn_global_load_lds(                                              \
        (const __attribute__((address_space(1))) void*)src,                        \
        (__attribute__((address_space(3))) void*)(KV + 16384 + (buf_) * 4096 + chb * 8), 16, 0, 0); \
  }

// one 64-key tile from K/V buffer CB_ (compile-time literal -> imm offsets)
#define COMPUTE(W_, CB_)                                                           \
  {                                                                                \
    f32x16 s = {};                                                                 \
    _Pragma("unroll")                                                              \
    for (int ks = 0; ks < 4; ++ks) {                                               \
      bf16x8 kf = *(const bf16x8*)(kp[ks] + (CB_) * 4096);                         \
      s = __builtin_amdgcn_mfma_f32_32x32x16_bf16(kf, qf[ks], s, 0, 0, 0);         \
    }                                                                              \
    unsigned half_ = hw ? (unsigned)((W_) >> 32) : (unsigned)(W_);                 \
    unsigned sh = half_ >> (hi5 * 4);                                              \
    bf16x8 pa0, pa1;                                                               \
    _Pragma("unroll")                                                              \
    for (int r = 0; r < 16; ++r) {                                                 \
      float p = __builtin_amdgcn_exp2f(s[r]);                                      \
      p = ((sh >> ((r & 3) + 8 * (r >> 2))) & 1u) ? p : 0.f;                       \
      int j = (r & 3) | ((r >> 3) << 2);                                           \
      if ((r >> 2) & 1) pa1[j] = (__bf16)p; else pa0[j] = (__bf16)p;               \
    }                                                                              \
    {                                                                              \
      bf16x8 vf0 = *(const bf16x8*)(vp[0] + (CB_) * 4096);                         \
      bf16x8 vf1 = *(const bf16x8*)(vp[1] + (CB_) * 4096);                         \
      o0 = __builtin_amdgcn_mfma_f32_32x32x16_bf16(pa0, vf0, o0, 0, 0, 0);         \
      o0 = __builtin_amdgcn_mfma_f32_32x32x16_bf16(pa1, vf1, o0, 0, 0, 0);         \
      bf16x8 vf2 = *(const bf16x8*)(vp[2] + (CB_) * 4096);                         \
      bf16x8 vf3 = *(const bf16x8*)(vp[3] + (CB_) * 4096);                         \
      o1 = __builtin_amdgcn_mfma_f32_32x32x16_bf16(pa0, vf2, o1, 0, 0, 0);         \
      o1 = __builtin_amdgcn_mfma_f32_32x32x16_bf16(pa1, vf3, o1, 0, 0, 0);         \
    }                                                                              \
    ols = __builtin_amdgcn_mfma_f32_32x32x16_bf16(pa0, onesf, ols, 0, 0, 0);       \
    ols = __builtin_amdgcn_mfma_f32_32x32x16_bf16(pa1, onesf, ols, 0, 0, 0);       \
  }

  // prologue: tiles 0,1 -> bufs 0,1
  if (hw == 1) { STAGE_K(0, 0); STAGE_K(1, 1); }
  else         { STAGE_V(0, 0); STAGE_V(1, 1); }
  u64x2 wmA = *(const u64x2*)(mrow);
  u64x2 wmB = {0, 0};
  __syncthreads();

  for (int p8 = 0; p8 < 8; ++p8) {
    const int t0 = p8 * 4;
    // period A: compute tiles t0,t0+1 (bufs 0,1); stage t0+2,t0+3 -> bufs 2,3
    if (hw == 1) { STAGE_K(t0 + 2, 2); STAGE_K(t0 + 3, 3); }
    else         { STAGE_V(t0 + 2, 2); STAGE_V(t0 + 3, 3); }
    wmB = *(const u64x2*)(mrow + t0 + 2);
    COMPUTE(wmA[0], 0);
    COMPUTE(wmA[1], 1);
    __syncthreads();
    // period B: compute tiles t0+2,t0+3 (bufs 2,3); stage t0+4,t0+5 -> bufs 0,1
    if (p8 < 7) {
      if (hw == 1) { STAGE_K(t0 + 4, 0); STAGE_K(t0 + 5, 1); }
      else         { STAGE_V(t0 + 4, 0); STAGE_V(t0 + 5, 1); }
      wmA = *(const u64x2*)(mrow + t0 + 4);
    }
    COMPUTE(wmB[0], 2);
    COMPUTE(wmB[1], 3);
    __syncthreads();
  }

  // ---- combine halves: hw=1 dumps partials, hw=0 adds + stores ----
  float* Sf  = (float*)KV;             // o partials: 8192 floats (32 KB)
  float* Sl  = Sf + 8192;              // lsum partials: 4096 floats (16 KB)
  if (hw == 1) {
#pragma unroll
    for (int r = 0; r < 16; ++r) {
      Sf[((wq * 2 + 0) * 16 + r) * 64 + lane] = o0[r];
      Sf[((wq * 2 + 1) * 16 + r) * 64 + lane] = o1[r];
      Sl[(wq * 16 + r) * 64 + lane] = ols[r];
    }
  }
  __syncthreads();
  if (hw == 0) {
#pragma unroll
    for (int r = 0; r < 16; ++r) {
      float po0 = Sf[((wq * 2 + 0) * 16 + r) * 64 + lane];
      float po1 = Sf[((wq * 2 + 1) * 16 + r) * 64 + lane];
      float pls = Sl[(wq * 16 + r) * 64 + lane];
      float inv = 1.f / (ols[r] + pls);
      int qr = (r & 3) + 8 * (r >> 2) + 4 * hi5;
      size_t ob = ((size_t)n * LSEQ + q0 + wq * 32 + qr) * 1024 + h * 64 + l31;
      out[ob]      = (o0[r] + po0) * inv;
      out[ob + 32] = (o1[r] + po1) * inv;
    }
  }
#undef STAGE_K
#undef STAGE_V
#undef COMPUTE
}

extern "C" void kernel_launch(void* const* d_in, const int* in_sizes, int n_in,
                              void* d_out, int out_size, void* d_ws, size_t ws_size,
                              hipStream_t stream) {
  const float* xv   = (const float*)d_in[0];   // values
  const float* xk   = (const float*)d_in[1];   // keys
  const float* xq   = (const float*)d_in[2];   // queries
  const int*   mask = (const int*)d_in[3];
  const float* Wv   = (const float*)d_in[4];
  const float* Wk   = (const float*)d_in[5];
  const float* Wq   = (const float*)d_in[6];
  float* out = (float*)d_out;

  const size_t elems = (size_t)NB * NH * LSEQ * HD;       // 4,194,304
  __bf16* Qw = (__bf16*)d_ws;
  __bf16* Kw = Qw + elems;
  __bf16* Vw = Kw + elems;          // holds permuted/transposed Vtp layout
  unsigned long long* mb = (unsigned long long*)(Vw + elems);  // 1 MB

  proj_kernel<<<dim3(64, NH, 4), 256, 0, stream>>>(xv, Wv, xk, Wk, xq, Wq, mask,
                                                   Vw, Kw, Qw, mb);
  attn_kernel<<<dim3(16, 32), 512, 0, stream>>>(Qw, Kw, Vw, mb, out);
}

// Round 17
// 84.048 us; speedup vs baseline: 1.0626x; 1.0280x over previous
//
#include <hip/hip_runtime.h>
#include <hip/hip_bf16.h>

// Problem constants (SelfAttention_773094113877)
#define LSEQ 2048
#define NB   2
#define NH   16
#define HD   64
#define NKT  32                      // LSEQ / 64 key-tiles
// Q is pre-scaled by log2(e)/sqrt(EMBED) in proj; attn uses native exp2.
#define QSCALE 0.04508687049285173f

typedef __attribute__((ext_vector_type(8)))  __bf16 bf16x8;
typedef __attribute__((ext_vector_type(4)))  __bf16 bf16x4;
typedef __attribute__((ext_vector_type(4)))  float  f32x4;
typedef __attribute__((ext_vector_type(16))) float  f32x16;
typedef __attribute__((ext_vector_type(2)))  unsigned long long u64x2;
typedef __attribute__((ext_vector_type(4)))  unsigned int u32x4;

// ------- fused pre-pass: proj (z=0,1,2) + mask bit-pack (z=3) -------
// proj: out[nh][l][d] = x @ W.T via MFMA bf16 split-3 (hi/lo), fp32-equivalent.
// V output (z==0) written TRANSPOSED + key-permuted + swizzle-baked for the
// 32x32 PV path: Vtp[d][c]: u=(c>>3)^swzV(d), j=c&7 ->
//   key = (u>>2)*32 + ((j&3) | ((u&1)<<2) | (((u>>1)&1)<<3) | ((j>>2)<<4))
// pack (z==3): mbits[g] = ballot(mask[g*64+lane] != 0), 32 words/wave.
__global__ __launch_bounds__(256)
void proj_kernel(const float* __restrict__ xv, const float* __restrict__ Wv_,
                 const float* __restrict__ xk, const float* __restrict__ Wk_,
                 const float* __restrict__ xq, const float* __restrict__ Wq_,
                 const int* __restrict__ mask,
                 __bf16* __restrict__ outv, __bf16* __restrict__ outk,
                 __bf16* __restrict__ outq,
                 unsigned long long* __restrict__ mbits) {
  __shared__ __bf16 S[16384];          // 32 KB: Xh|Xl|Wh|Wl; tb aliases Xh/Xl

  const int tid = threadIdx.x;

  if (blockIdx.z == 3) {
    // ---- mask bit-pack: 1024 blocks x 8192 ints each ----
    const int bid  = blockIdx.x * NH + blockIdx.y;     // 0..1023
    const int w    = tid >> 6;
    const int lane = tid & 63;
    const size_t wbase = (size_t)bid * 128 + w * 32;   // word index base
#pragma unroll
    for (int i = 0; i < 8; ++i) {
      size_t g0 = wbase + i * 4;
#pragma unroll
      for (int j = 0; j < 4; ++j) {
        int v = mask[(g0 + j) * 64 + lane];
        unsigned long long b = __ballot(v != 0);
        if (lane == 0) mbits[g0 + j] = b;
      }
    }
    return;
  }

  __bf16* Xh = S;
  __bf16* Xl = S + 4096;
  __bf16* Wh = S + 8192;
  __bf16* Wl = S + 12288;

  const float* x; const float* W; __bf16* out;
  if (blockIdx.z == 0)      { x = xv; W = Wv_; out = outv; }
  else if (blockIdx.z == 1) { x = xk; W = Wk_; out = outk; }
  else                      { x = xq; W = Wq_; out = outq; }
  const float osc = (blockIdx.z == 2) ? QSCALE : 1.0f;

  const int bx = blockIdx.x;
  const int h  = blockIdx.y;
  const int n  = bx >> 5;
  const int l0 = (bx & 31) << 6;

  const int r  = tid >> 2;
  const int c0 = (tid & 3) << 4;
  const float* xrow = x + ((size_t)(n * LSEQ + l0) + r) * 1024 + h * 64 + c0;
  const float* wrow = W + r * 64 + c0;

#pragma unroll
  for (int hf = 0; hf < 2; ++hf) {
    int kc = c0 + hf * 8;
    int off = r * 64 + (kc ^ ((r & 7) << 3));
    float4 a = *(const float4*)(xrow + hf * 8);
    float4 b = *(const float4*)(xrow + hf * 8 + 4);
    float va[8] = {a.x, a.y, a.z, a.w, b.x, b.y, b.z, b.w};
    bf16x8 hi, lo;
#pragma unroll
    for (int j = 0; j < 8; ++j) {
      __bf16 h_ = (__bf16)va[j];
      hi[j] = h_;
      lo[j] = (__bf16)(va[j] - (float)h_);
    }
    *(bf16x8*)(Xh + off) = hi;
    *(bf16x8*)(Xl + off) = lo;

    float4 c = *(const float4*)(wrow + hf * 8);
    float4 d = *(const float4*)(wrow + hf * 8 + 4);
    float vw[8] = {c.x, c.y, c.z, c.w, d.x, d.y, d.z, d.w};
    bf16x8 whv, wlv;
#pragma unroll
    for (int j = 0; j < 8; ++j) {
      __bf16 h_ = (__bf16)vw[j];
      whv[j] = h_;
      wlv[j] = (__bf16)(vw[j] - (float)h_);
    }
    *(bf16x8*)(Wh + off) = whv;
    *(bf16x8*)(Wl + off) = wlv;
  }
  __syncthreads();

  const int wv   = tid >> 6;
  const int lane = tid & 63;
  const int l15  = lane & 15;
  const int lhi  = lane >> 4;

  bf16x8 xhf[2], xlf[2];
  const int arow = wv * 16 + l15;
#pragma unroll
  for (int ko = 0; ko < 2; ++ko) {
    int aoff = arow * 64 + ((ko * 32 + lhi * 8) ^ ((arow & 7) << 3));
    xhf[ko] = *(const bf16x8*)(Xh + aoff);
    xlf[ko] = *(const bf16x8*)(Xl + aoff);
  }

  f32x4 acc[4] = {};
#pragma unroll
  for (int cg = 0; cg < 4; ++cg) {
    int d = cg * 16 + l15;
#pragma unroll
    for (int ko = 0; ko < 2; ++ko) {
      int boff = d * 64 + ((ko * 32 + lhi * 8) ^ ((d & 7) << 3));
      bf16x8 whf = *(const bf16x8*)(Wh + boff);
      bf16x8 wlf = *(const bf16x8*)(Wl + boff);
      acc[cg] = __builtin_amdgcn_mfma_f32_16x16x32_bf16(xhf[ko], whf, acc[cg], 0, 0, 0);
      acc[cg] = __builtin_amdgcn_mfma_f32_16x16x32_bf16(xhf[ko], wlf, acc[cg], 0, 0, 0);
      acc[cg] = __builtin_amdgcn_mfma_f32_16x16x32_bf16(xlf[ko], whf, acc[cg], 0, 0, 0);
    }
  }
  __syncthreads();

  __bf16* tb = S;                      // [64][72] = [token(key-in-tile)][d]
#pragma unroll
  for (int cg = 0; cg < 4; ++cg)
#pragma unroll
    for (int rr = 0; rr < 4; ++rr)
      tb[(wv * 16 + lhi * 4 + rr) * 72 + cg * 16 + l15] = (__bf16)(acc[cg][rr] * osc);
  __syncthreads();

  if (blockIdx.z == 0) {
    // ---- V: transposed + permuted (32x32 PV mapping) + swizzle-baked ----
    const int d   = tid >> 2;
    const int cg  = tid & 3;
    const int swz = (d & 7) ^ ((d >> 3) & 7);
    __bf16* vout = out + (size_t)(n * NH + h) * (LSEQ * HD)
                 + (size_t)(bx & 31) * 4096 + d * 64 + cg * 16;
    bf16x8 s0, s1;
#pragma unroll
    for (int j16 = 0; j16 < 16; ++j16) {
      int c = cg * 16 + j16;
      int u = (c >> 3) ^ swz;
      int j = c & 7;
      int key = ((u >> 2) << 5) | (j & 3) | ((u & 1) << 2)
              | (((u >> 1) & 1) << 3) | ((j >> 2) << 4);
      __bf16 v_ = tb[key * 72 + d];
      if (j16 < 8) s0[j16] = v_; else s1[j16 - 8] = v_;
    }
    *(bf16x8*)(vout)     = s0;
    *(bf16x8*)(vout + 8) = s1;
  } else {
    const int tok = tid >> 2;
    const int d0  = (tid & 3) * 16;
    bf16x8 o0 = *(const bf16x8*)(tb + tok * 72 + d0);
    bf16x8 o1 = *(const bf16x8*)(tb + tok * 72 + d0 + 8);
    size_t ob = (size_t)(n * NH + h) * LSEQ + l0;
    *(bf16x8*)(out + (ob + tok) * HD + d0)     = o0;
    *(bf16x8*)(out + (ob + tok) * HD + d0 + 8) = o1;
  }
}

// ---------------- fused flash attention (32x32x16 MFMA) ----------------
// grid (16, 32) = 512 blocks, 512 threads = 8 waves.
// K-split: wave = (hw, wq); hw = key-half (32 keys), wq = q-group (32 rows).
// hw=1 waves stage K, hw=0 stage V (both global_load_lds; V pre-permuted).
// 4 K bufs + 4 V bufs (64 KB), one barrier per two 64-key tiles (R11).
// SOFTMAX DIET: mask via sign-extend AND (v_bfe_i32 + v_and on the f32 exp
// result — 0/-1 mask, exact) and pairwise __float22bfloat162_rn conversion
// (lets backend emit v_cvt_pk_bf16_f32). Math bit-identical to cndmask path.
// QK: S^T = K·Q^T 32x32x16 ×4. q lane-local -> 1 mask word/lane/tile.
// P->PV A-operand lane-local via V key-permutation (baked in proj).
// lsum via MFMA ones. exp2 native; Q pre-scaled.
__global__ __launch_bounds__(512, 4)
void attn_kernel(const __bf16* __restrict__ Qb, const __bf16* __restrict__ Kb,
                 const __bf16* __restrict__ Vtp,
                 const unsigned long long* __restrict__ mbits,
                 float* __restrict__ out) {
  __shared__ __bf16 KV[32768];   // K bufs 0-3 @ b*4096 ; V bufs 0-3 @ 16384+b*4096

  const int tid  = threadIdx.x;
  const int wid  = tid >> 6;
  const int hw   = wid >> 2;           // key-half (0/1)
  const int wq   = wid & 3;            // q-row group
  const int lane = tid & 63;
  const int l31  = lane & 31;
  const int hi5  = lane >> 5;

  // XCD-bijective swizzle: 64 blocks/XCD = 4 heads x 16 q-tiles per XCD
  const int lin = blockIdx.y * 16 + blockIdx.x;    // 0..511
  const int xcd = lin & 7;
  const int idx = lin >> 3;                        // 0..63
  const int nh  = xcd + ((idx >> 4) << 3);
  const int qt  = idx & 15;
  const int n   = nh >> 4;
  const int h   = nh & 15;
  const int q0  = qt << 7;                         // 128 q-rows per block

  const __bf16* Qg = Qb + ((size_t)nh * LSEQ + q0) * HD;
  const __bf16* Kg = Kb + (size_t)nh * LSEQ * HD;
  const __bf16* Vg = Vtp + (size_t)nh * LSEQ * HD;   // [kt][d][col] permuted

  // Q regs (pre-scaled): qrow = wq*32 + l31, dims hi5*8 + 16*ks (ks=0..3)
  const int qrow = wq * 32 + l31;
  bf16x8 qf[4];
#pragma unroll
  for (int ks = 0; ks < 4; ++ks)
    qf[ks] = *(const bf16x8*)(Qg + (size_t)qrow * HD + ks * 16 + hi5 * 8);

  f32x16 o0 = {}, o1 = {}, ols = {};
  const unsigned long long* mrow =
      mbits + ((size_t)n * LSEQ + q0 + qrow) * NKT;

  bf16x8 onesf;
#pragma unroll
  for (int j = 0; j < 8; ++j) onesf[j] = (__bf16)1.0f;

  // ---- hoisted per-lane LDS pointers (buffer 0 bases; buf b = +b*4096) ----
  const int key = hw * 32 + l31;
  const __bf16* kp[4];
#pragma unroll
  for (int ks = 0; ks < 4; ++ks)
    kp[ks] = &KV[key * 64 + (((2 * ks + hi5) ^ (key & 7)) << 3)];
  const __bf16* vp[4];
#pragma unroll
  for (int dh = 0; dh < 2; ++dh) {
    int d = dh * 32 + l31;
    int swz = (d & 7) ^ ((d >> 3) & 7);
    vp[dh * 2 + 0] = &KV[16384 + d * 64 + (((hw * 4 + hi5) ^ swz) << 3)];
    vp[dh * 2 + 1] = &KV[16384 + d * 64 + (((hw * 4 + 2 + hi5) ^ swz) << 3)];
  }

#define STAGE_K(kt_, buf_)                                                         \
  _Pragma("unroll")                                                                \
  for (int it = 0; it < 2; ++it) {                                                 \
    int chb = wq * 64 + it * 256;                                                  \
    int ch = chb + lane;                                                           \
    int skey = ch >> 3, sdc = ch & 7;                                              \
    const __bf16* src = Kg + (size_t)(kt_) * 4096 + skey * 64 + ((sdc ^ (skey & 7)) << 3); \
    __builtin_amdgcn_global_load_lds(                                              \
        (const __attribute__((address_space(1))) void*)src,                        \
        (__attribute__((address_space(3))) void*)(KV + (buf_) * 4096 + chb * 8), 16, 0, 0); \
  }
#define STAGE_V(kt_, buf_)                                                         \
  _Pragma("unroll")                                                                \
  for (int it = 0; it < 2; ++it) {                                                 \
    int chb = wq * 64 + it * 256;                                                  \
    int ch = chb + lane;                                                           \
    const __bf16* src = Vg + (size_t)(kt_) * 4096 + ch * 8;                        \
    __builtin_amdgcn_global_load_lds(                                              \
        (const __attribute__((address_space(1))) void*)src,                        \
        (__attribute__((address_space(3))) void*)(KV + 16384 + (buf_) * 4096 + chb * 8), 16, 0, 0); \
  }

// masked-exp pair -> packed 2xbf16 word. ra_, rb_ compile-time; mask bits
// c = (r&3)+8*(r>>2). Sign-extend bit to 0/-1 (v_bfe_i32) and AND the
// positive exp result: exact 0 or unchanged.
#define PAIRW(s_, sh_, ra_, rb_, dstw_)                                            \
  {                                                                                \
    float pa_ = __builtin_amdgcn_exp2f(s_[ra_]);                                   \
    float pb_ = __builtin_amdgcn_exp2f(s_[rb_]);                                   \
    int ma_ = ((int)((sh_) << (31 - (((ra_) & 3) + 8 * ((ra_) >> 2))))) >> 31;     \
    int mb_ = ((int)((sh_) << (31 - (((rb_) & 3) + 8 * ((rb_) >> 2))))) >> 31;     \
    unsigned ua_ = __float_as_uint(pa_) & (unsigned)ma_;                           \
    unsigned ub_ = __float_as_uint(pb_) & (unsigned)mb_;                           \
    union { __hip_bfloat162 h2; unsigned u; } cv_;                                 \
    cv_.h2 = __float22bfloat162_rn(make_float2(__uint_as_float(ua_),               \
                                               __uint_as_float(ub_)));             \
    dstw_ = cv_.u;                                                                 \
  }

// one 64-key tile from K/V buffer CB_ (compile-time literal -> imm offsets)
#define COMPUTE(W_, CB_)                                                           \
  {                                                                                \
    f32x16 s = {};                                                                 \
    _Pragma("unroll")                                                              \
    for (int ks = 0; ks < 4; ++ks) {                                               \
      bf16x8 kf = *(const bf16x8*)(kp[ks] + (CB_) * 4096);                         \
      s = __builtin_amdgcn_mfma_f32_32x32x16_bf16(kf, qf[ks], s, 0, 0, 0);         \
    }                                                                              \
    unsigned half_ = hw ? (unsigned)((W_) >> 32) : (unsigned)(W_);                 \
    unsigned sh = half_ >> (hi5 * 4);                                              \
    u32x4 w0_, w1_;                                                                \
    PAIRW(s, sh, 0, 1,  w0_[0]); PAIRW(s, sh, 2, 3,  w0_[1]);                      \
    PAIRW(s, sh, 8, 9,  w0_[2]); PAIRW(s, sh, 10, 11, w0_[3]);                     \
    PAIRW(s, sh, 4, 5,  w1_[0]); PAIRW(s, sh, 6, 7,  w1_[1]);                      \
    PAIRW(s, sh, 12, 13, w1_[2]); PAIRW(s, sh, 14, 15, w1_[3]);                    \
    bf16x8 pa0 = *(bf16x8*)&w0_;                                                   \
    bf16x8 pa1 = *(bf16x8*)&w1_;                                                   \
    {                                                                              \
      bf16x8 vf0 = *(const bf16x8*)(vp[0] + (CB_) * 4096);                         \
      bf16x8 vf1 = *(const bf16x8*)(vp[1] + (CB_) * 4096);                         \
      o0 = __builtin_amdgcn_mfma_f32_32x32x16_bf16(pa0, vf0, o0, 0, 0, 0);         \
      o0 = __builtin_amdgcn_mfma_f32_32x32x16_bf16(pa1, vf1, o0, 0, 0, 0);         \
      bf16x8 vf2 = *(const bf16x8*)(vp[2] + (CB_) * 4096);                         \
      bf16x8 vf3 = *(const bf16x8*)(vp[3] + (CB_) * 4096);                         \
      o1 = __builtin_amdgcn_mfma_f32_32x32x16_bf16(pa0, vf2, o1, 0, 0, 0);         \
      o1 = __builtin_amdgcn_mfma_f32_32x32x16_bf16(pa1, vf3, o1, 0, 0, 0);         \
    }                                                                              \
    ols = __builtin_amdgcn_mfma_f32_32x32x16_bf16(pa0, onesf, ols, 0, 0, 0);       \
    ols = __builtin_amdgcn_mfma_f32_32x32x16_bf16(pa1, onesf, ols, 0, 0, 0);       \
  }

  // prologue: tiles 0,1 -> bufs 0,1
  if (hw == 1) { STAGE_K(0, 0); STAGE_K(1, 1); }
  else         { STAGE_V(0, 0); STAGE_V(1, 1); }
  u64x2 wmA = *(const u64x2*)(mrow);
  u64x2 wmB = {0, 0};
  __syncthreads();

  for (int p8 = 0; p8 < 8; ++p8) {
    const int t0 = p8 * 4;
    // period A: compute tiles t0,t0+1 (bufs 0,1); stage t0+2,t0+3 -> bufs 2,3
    if (hw == 1) { STAGE_K(t0 + 2, 2); STAGE_K(t0 + 3, 3); }
    else         { STAGE_V(t0 + 2, 2); STAGE_V(t0 + 3, 3); }
    wmB = *(const u64x2*)(mrow + t0 + 2);
    COMPUTE(wmA[0], 0);
    COMPUTE(wmA[1], 1);
    __syncthreads();
    // period B: compute tiles t0+2,t0+3 (bufs 2,3); stage t0+4,t0+5 -> bufs 0,1
    if (p8 < 7) {
      if (hw == 1) { STAGE_K(t0 + 4, 0); STAGE_K(t0 + 5, 1); }
      else         { STAGE_V(t0 + 4, 0); STAGE_V(t0 + 5, 1); }
      wmA = *(const u64x2*)(mrow + t0 + 4);
    }
    COMPUTE(wmB[0], 2);
    COMPUTE(wmB[1], 3);
    __syncthreads();
  }

  // ---- combine halves: hw=1 dumps partials, hw=0 adds + stores ----
  float* Sf  = (float*)KV;             // o partials: 8192 floats (32 KB)
  float* Sl  = Sf + 8192;              // lsum partials: 4096 floats (16 KB)
  if (hw == 1) {
#pragma unroll
    for (int r = 0; r < 16; ++r) {
      Sf[((wq * 2 + 0) * 16 + r) * 64 + lane] = o0[r];
      Sf[((wq * 2 + 1) * 16 + r) * 64 + lane] = o1[r];
      Sl[(wq * 16 + r) * 64 + lane] = ols[r];
    }
  }
  __syncthreads();
  if (hw == 0) {
#pragma unroll
    for (int r = 0; r < 16; ++r) {
      float po0 = Sf[((wq * 2 + 0) * 16 + r) * 64 + lane];
      float po1 = Sf[((wq * 2 + 1) * 16 + r) * 64 + lane];
      float pls = Sl[(wq * 16 + r) * 64 + lane];
      float inv = 1.f / (ols[r] + pls);
      int qr = (r & 3) + 8 * (r >> 2) + 4 * hi5;
      size_t ob = ((size_t)n * LSEQ + q0 + wq * 32 + qr) * 1024 + h * 64 + l31;
      out[ob]      = (o0[r] + po0) * inv;
      out[ob + 32] = (o1[r] + po1) * inv;
    }
  }
#undef STAGE_K
#undef STAGE_V
#undef PAIRW
#undef COMPUTE
}

extern "C" void kernel_launch(void* const* d_in, const int* in_sizes, int n_in,
                              void* d_out, int out_size, void* d_ws, size_t ws_size,
                              hipStream_t stream) {
  const float* xv   = (const float*)d_in[0];   // values
  const float* xk   = (const float*)d_in[1];   // keys
  const float* xq   = (const float*)d_in[2];   // queries
  const int*   mask = (const int*)d_in[3];
  const float* Wv   = (const float*)d_in[4];
  const float* Wk   = (const float*)d_in[5];
  const float* Wq   = (const float*)d_in[6];
  float* out = (float*)d_out;

  const size_t elems = (size_t)NB * NH * LSEQ * HD;       // 4,194,304
  __bf16* Qw = (__bf16*)d_ws;
  __bf16* Kw = Qw + elems;
  __bf16* Vw = Kw + elems;          // holds permuted/transposed Vtp layout
  unsigned long long* mb = (unsigned long long*)(Vw + elems);  // 1 MB

  proj_kernel<<<dim3(64, NH, 4), 256, 0, stream>>>(xv, Wv, xk, Wk, xq, Wq, mask,
                                                   Vw, Kw, Qw, mb);
  attn_kernel<<<dim3(16, 32), 512, 0, stream>>>(Qw, Kw, Vw, mb, out);
}